// Round 6
// baseline (163.841 us; speedup 1.0000x reference)
//
#include <hip/hip_runtime.h>

typedef _Float16 half8 __attribute__((ext_vector_type(8)));
typedef float f32x4 __attribute__((ext_vector_type(4)));

#define SPH  64           // timesteps per phase (R17: doubled to amortize per-phase overhead)
#define NIT  18           // 16 compute phases + 2 pipeline-drain iterations
#define SPKW 392          // spk row stride f16: 384 + 8 pad (784 B rows, 16B-aligned)
#define XTW  68           // xsT row stride (floats): 272 B rows, 16B-aligned cols
#define C2W  48           // c2L row stride (floats)
#define TN   1000

// R17: amortize the per-phase serialization floor. R12-R16 evidence: phase
// stuck at ~6.1-6.5k cyc while aggregate LDS work went 6.4k->3.8k cyc ->
// aggregate-throughput model falsified; ~2.3k cyc/phase is overhead
// (post-barrier read bursts, per-block read-wait serialization, barrier).
// Changes: SPH 32->64 (half the phases, half the overhead events), conv
// reads explicitly 2-block-deep software-pipelined (bufA/bufB rotation),
// scan on its own wave, GEMM waves each run 2 t-blocks (A-frags shared).
// LDS 141KB (<160KB), 1 block/CU as before. Numerics identical to R16.
//   waves 0-2 (192 thr): conv+LIF1(ph), 2 channels/thread (cpair=ct&7, p=ct>>3)
//   waves 3-8 (384 thr): FC GEMM(ph-1): 2 tasks (m=g%3, tb=g/3 and g/3+2):
//                        2x(12 B-loads + 12 MFMA + 1 store) + xsT staging
//                        (5 floats/thread, 2-phase-deep load/store pipeline)
//   wave 9    (64 thr):  LIF2 scan(ph-2) + final output.
// One barrier per iteration; producer->consumer 1 barrier apart.
__global__ __launch_bounds__(640, 1) void snn_fwd(
    const float* __restrict__ x,      // (256,1000,30)
    const float* __restrict__ conv_w, // (16,1,7)
    const float* __restrict__ conv_b, // (16)
    const float* __restrict__ fc_w,   // (35,384)
    const float* __restrict__ fc_b,   // (35)
    float* __restrict__ out)          // (256,35)
{
    __shared__ __align__(16) _Float16 spk[2][SPH][SPKW];   // 100352 B
    __shared__ __align__(16) float    xsT[2][30][XTW];     //  16320 B
    __shared__ __align__(16) float    c2L[2][SPH][C2W];    //  24576 B

    const int tid  = threadIdx.x;
    const int b    = blockIdx.x;
    const int wid  = tid >> 6;
    const int lane = tid & 63;

    // ---------- conv setup (wid<3): thread = (cpair=ct&7, p=ct>>3), 2 channels ----------
    const int ct    = tid;           // 0..191 when wid<3
    const int cpair = ct & 7;
    const int p     = ct >> 3;       // 0..23
    const int c0    = cpair * 2;
    float wk0[7], wk1[7];
    float cb0 = 0.f, cb1 = 0.f;
    if (wid < 3) {
#pragma unroll
        for (int k = 0; k < 7; ++k) {
            wk0[k] = conv_w[c0 * 7 + k];
            wk1[k] = conv_w[(c0 + 1) * 7 + k];
        }
        cb0 = conv_b[c0];
        cb1 = conv_b[c0 + 1];
    }

    // ---------- FC setup (wid 3..8): m = g%3, t-blocks tb0 and tb0+2 ----------
    const int g   = wid - 3;
    const int m   = g % 3;
    const int tb0 = g / 3;           // 0 or 1; second task uses tb0+2
    const int nL  = lane & 15;       // B col (t_local); C col
    const int q   = lane >> 4;       // quad: k = q*8 + j
    half8 A[12];
    if (wid >= 3 && wid < 9) {
        const int o = m * 16 + nL;
#pragma unroll
        for (int kt = 0; kt < 12; ++kt) {
            half8 a;
#pragma unroll
            for (int j = 0; j < 8; ++j) {
                int Kp = kt * 32 + q * 8 + j;    // permuted K index (p*16+c)
                int Kc = Kp & 15;                 // channel
                int Kq = Kp >> 4;                 // position
                a[j] = (o < 35) ? (_Float16)fc_w[o * 384 + Kc * 24 + Kq]
                                : (_Float16)0.f;
            }
            A[kt] = a;
        }
    }
    const float fcb = (wid == 9 && lane < 35) ? fc_b[lane] : 0.f;

    // ---------- staging setup (wid 3..8): st in 0..383, 5 floats each ----------
    const int st = tid - 192;
    int fs[5], fl[5];
    if (wid >= 3 && wid < 9) {
#pragma unroll
        for (int r = 0; r < 5; ++r) {
            int f = st + 384 * r;    // 0..1919, exactly covers 64*30
            fs[r] = f / 30;          // t_local 0..63
            fl[r] = f % 30;          // position 0..29
        }
    }

    // ---------- state ----------
    float m1a = 0.f, spa = 0.f;      // LIF1 channel c0
    float m1b = 0.f, spb = 0.f;      // LIF1 channel c0+1
    float mem2 = 0.f, accO = 0.f;    // LIF2 (wave9 lanes<35)
    float xr[5];                     // staging regs, data phase ph+1

    const float* xb = x + (size_t)b * (TN * 30);

    // ---------- prologue (wid 3..8): stage xsT[0]; load regs for data phase 1 ----------
    if (wid >= 3 && wid < 9) {
#pragma unroll
        for (int r = 0; r < 5; ++r) {
            int f = st + 384 * r;
            xsT[0][fl[r]][fs[r]] = xb[f];          // t 0..63 < TN
        }
#pragma unroll
        for (int r = 0; r < 5; ++r) {
            int f = st + 384 * r;
            xr[r] = xb[1920 + f];                  // t 64..127 < TN
        }
    }
    __syncthreads();

#pragma unroll 1
    for (int ph = 0; ph < NIT; ++ph) {
        if (wid < 3) {
            // ========= conv+LIF1(ph): 16 blocks of 4 steps, 2-deep read pipeline =========
            if (ph < 16) {
                const float* xcol = &xsT[ph & 1][p][0];
                unsigned int* sdst =
                    (unsigned int*)&spk[ph & 1][0][p * 16 + c0];

                auto conv4 = [&](const f32x4* bf, int sb) {
                    float ca[4], cc[4];
#pragma unroll
                    for (int dt = 0; dt < 4; ++dt) { ca[dt] = cb0; cc[dt] = cb1; }
#pragma unroll
                    for (int k = 0; k < 7; ++k) {
#pragma unroll
                        for (int dt = 0; dt < 4; ++dt) {
                            ca[dt] = fmaf(wk0[k], bf[k][dt], ca[dt]);
                            cc[dt] = fmaf(wk1[k], bf[k][dt], cc[dt]);
                        }
                    }
#pragma unroll
                    for (int dt = 0; dt < 4; ++dt) {
                        m1a = fmaf(0.9f, m1a, ca[dt] - spa);
                        spa = (m1a > 1.0f) ? 1.0f : 0.0f;
                        m1b = fmaf(0.9f, m1b, cc[dt] - spb);
                        spb = (m1b > 1.0f) ? 1.0f : 0.0f;
                        unsigned int pk = (m1a > 1.0f ? 0x00003C00u : 0u) |
                                          (m1b > 1.0f ? 0x3C000000u : 0u);
                        sdst[(sb + dt) * (SPKW / 2)] = pk;
                    }
                };

                f32x4 bA[7], bB[7];
#pragma unroll
                for (int k = 0; k < 7; ++k)
                    bA[k] = *(const f32x4*)(xcol + k * XTW);
#pragma unroll 2
                for (int blk = 0; blk < 16; blk += 2) {
                    const int sB = (blk + 1) * 4;
#pragma unroll
                    for (int k = 0; k < 7; ++k)
                        bB[k] = *(const f32x4*)(xcol + k * XTW + sB);
                    conv4(bA, blk * 4);
                    const int sA = (blk + 2 < 16) ? (blk + 2) * 4 : 60;
#pragma unroll
                    for (int k = 0; k < 7; ++k)
                        bA[k] = *(const f32x4*)(xcol + k * XTW + sA);
                    conv4(bB, sB);
                }
            }
        } else if (wid < 9) {
            // ====== staging loads for data phase ph+2 issued first (latency) ======
            const bool ldg = (ph <= 13);
            float xn[5];
            if (ldg) {
                const float* src = xb + (size_t)(ph + 2) * (SPH * 30);
#pragma unroll
                for (int r = 0; r < 5; ++r) {
                    int f = st + 384 * r;
                    int t = (ph + 2) * SPH + fs[r];
                    xn[r] = (t < TN) ? src[f] : 0.f;
                }
            }
            // =================== GEMM(ph-1): tasks (m, tb0) and (m, tb0+2) ===================
            if (ph >= 1 && ph <= 16) {
                const _Float16* sb = &spk[(ph - 1) & 1][0][0];
                float* cd = &c2L[(ph - 1) & 1][0][0];
#pragma unroll
                for (int task = 0; task < 2; ++task) {
                    const int tb = tb0 + task * 2;      // 0..3
                    half8 B[12];
#pragma unroll
                    for (int kt = 0; kt < 12; ++kt)
                        B[kt] = *(const half8*)(sb + (tb * 16 + nL) * SPKW + kt * 32 + q * 8);
                    f32x4 acc = {0.f, 0.f, 0.f, 0.f};
#pragma unroll
                    for (int kt = 0; kt < 12; ++kt)
                        acc = __builtin_amdgcn_mfma_f32_16x16x32_f16(A[kt], B[kt], acc, 0, 0, 0);
                    // C/D: col = lane&15 (t_local), row = q*4+i (o_local)
                    *(f32x4*)(cd + (tb * 16 + nL) * C2W + m * 16 + q * 4) = acc;
                }
            }
            // ====== staging store (data ph+1, loaded last phase); then rotate ======
            if (ph <= 14) {
                float* dst = &xsT[(ph + 1) & 1][0][0];
#pragma unroll
                for (int r = 0; r < 5; ++r)
                    dst[fl[r] * XTW + fs[r]] = xr[r];
            }
            if (ldg) {
#pragma unroll
                for (int r = 0; r < 5; ++r) xr[r] = xn[r];
            }
        } else {
            // =================== LIF2 scan(ph-2) (wave 9 lanes<35) ===================
            if (lane < 35 && ph >= 2) {
                const float* cs = &c2L[(ph - 2) & 1][0][0];
                const int tbase = (ph - 2) * SPH;
#pragma unroll
                for (int jc = 0; jc < SPH; jc += 16) {
                    float v[16];
#pragma unroll
                    for (int u = 0; u < 16; ++u)
                        v[u] = cs[(jc + u) * C2W + lane];
#pragma unroll
                    for (int u = 0; u < 16; ++u) {
                        float r2 = (mem2 > 1.0f) ? 1.0f : 0.0f;
                        mem2 = 0.9f * mem2 + (v[u] + fcb) - r2;
                        if (tbase + jc + u < TN) accO += mem2;
                    }
                }
            }
        }
        __syncthreads();
    }

    if (wid == 9 && lane < 35) out[b * 35 + lane] = accO * (1.0f / (float)TN);
}

extern "C" void kernel_launch(void* const* d_in, const int* in_sizes, int n_in,
                              void* d_out, int out_size, void* d_ws, size_t ws_size,
                              hipStream_t stream) {
    const float* x      = (const float*)d_in[0];
    const float* conv_w = (const float*)d_in[1];
    const float* conv_b = (const float*)d_in[2];
    const float* fc_w   = (const float*)d_in[3];
    const float* fc_b   = (const float*)d_in[4];
    float* out          = (float*)d_out;

    snn_fwd<<<256, 640, 0, stream>>>(x, conv_w, conv_b, fc_w, fc_b, out);
}

// Round 7
// 162.676 us; speedup vs baseline: 1.0072x; 1.0072x over previous
//
#include <hip/hip_runtime.h>

typedef _Float16 half8 __attribute__((ext_vector_type(8)));
typedef float f32x4 __attribute__((ext_vector_type(4)));

#define SPH  64           // timesteps per phase
#define NIT  18           // 16 compute phases + 2 pipeline-drain iterations
#define SPKW 392          // spk row stride f16: 384 + 8 pad (784 B rows, 16B-aligned)
#define XTW  68           // xsT row stride (floats): 272 B rows, 16B-aligned cols
#define C2W  48           // c2L row stride (floats)
#define TN   1000

// R18: clean retest of R17 (SPH=64, conv 2-deep pipeline). R17's traffic
// anomaly (WRITE 42KB->24.6MB, FETCH +7MB) is attributed to rule #20: the
// conv4 lambda's pointer param demoted bufA/bufB to scratch. This version
// uses macros over NAMED register arrays, all indices compile-time. If
// traffic normalizes and time drops -> per-phase-overhead theory confirmed;
// if traffic normalizes and time is ~86us -> theory dead (conv serial chain
// is the floor); if traffic still bad -> SPH=64/141KB-LDS has a HW cost.
//   waves 0-2 (192 thr): conv+LIF1(ph), 2 channels/thread (cpair=ct&7, p=ct>>3)
//   waves 3-8 (384 thr): FC GEMM(ph-1): 2 tasks (m=g%3, tb=g/3, g/3+2)
//                        + xsT staging (5 floats/thread, 2-phase pipeline)
//   wave 9    (64 thr):  LIF2 scan(ph-2) + final output.
// One barrier per iteration; producer->consumer 1 barrier apart.

#define LOADBLK(BUF, S)                                                 \
    _Pragma("unroll")                                                   \
    for (int k = 0; k < 7; ++k)                                         \
        BUF[k] = *(const f32x4*)(xcol + k * XTW + (S));

#define CONV4(BUF, SB)                                                  \
    {                                                                   \
        float ca[4], cc[4];                                             \
        _Pragma("unroll")                                               \
        for (int dt = 0; dt < 4; ++dt) { ca[dt] = cb0; cc[dt] = cb1; }  \
        _Pragma("unroll")                                               \
        for (int k = 0; k < 7; ++k) {                                   \
            _Pragma("unroll")                                           \
            for (int dt = 0; dt < 4; ++dt) {                            \
                ca[dt] = fmaf(wk0[k], BUF[k][dt], ca[dt]);              \
                cc[dt] = fmaf(wk1[k], BUF[k][dt], cc[dt]);              \
            }                                                           \
        }                                                               \
        _Pragma("unroll")                                               \
        for (int dt = 0; dt < 4; ++dt) {                                \
            m1a = fmaf(0.9f, m1a, ca[dt] - spa);                        \
            spa = (m1a > 1.0f) ? 1.0f : 0.0f;                           \
            m1b = fmaf(0.9f, m1b, cc[dt] - spb);                        \
            spb = (m1b > 1.0f) ? 1.0f : 0.0f;                           \
            unsigned int pk = (m1a > 1.0f ? 0x00003C00u : 0u) |         \
                              (m1b > 1.0f ? 0x3C000000u : 0u);          \
            sdst[((SB) + dt) * (SPKW / 2)] = pk;                        \
        }                                                               \
    }

__global__ __launch_bounds__(640, 1) void snn_fwd(
    const float* __restrict__ x,      // (256,1000,30)
    const float* __restrict__ conv_w, // (16,1,7)
    const float* __restrict__ conv_b, // (16)
    const float* __restrict__ fc_w,   // (35,384)
    const float* __restrict__ fc_b,   // (35)
    float* __restrict__ out)          // (256,35)
{
    __shared__ __align__(16) _Float16 spk[2][SPH][SPKW];   // 100352 B
    __shared__ __align__(16) float    xsT[2][30][XTW];     //  16320 B
    __shared__ __align__(16) float    c2L[2][SPH][C2W];    //  24576 B

    const int tid  = threadIdx.x;
    const int b    = blockIdx.x;
    const int wid  = tid >> 6;
    const int lane = tid & 63;

    // ---------- conv setup (wid<3): thread = (cpair=ct&7, p=ct>>3), 2 channels ----------
    const int ct    = tid;           // 0..191 when wid<3
    const int cpair = ct & 7;
    const int p     = ct >> 3;       // 0..23
    const int c0    = cpair * 2;
    float wk0[7], wk1[7];
    float cb0 = 0.f, cb1 = 0.f;
    if (wid < 3) {
#pragma unroll
        for (int k = 0; k < 7; ++k) {
            wk0[k] = conv_w[c0 * 7 + k];
            wk1[k] = conv_w[(c0 + 1) * 7 + k];
        }
        cb0 = conv_b[c0];
        cb1 = conv_b[c0 + 1];
    }

    // ---------- FC setup (wid 3..8): m = g%3, t-blocks tb0 and tb0+2 ----------
    const int g   = wid - 3;
    const int m   = g % 3;
    const int tb0 = g / 3;           // 0 or 1; second task uses tb0+2
    const int nL  = lane & 15;       // B col (t_local); C col
    const int q   = lane >> 4;       // quad: k = q*8 + j
    half8 A[12];
    if (wid >= 3 && wid < 9) {
        const int o = m * 16 + nL;
#pragma unroll
        for (int kt = 0; kt < 12; ++kt) {
            half8 a;
#pragma unroll
            for (int j = 0; j < 8; ++j) {
                int Kp = kt * 32 + q * 8 + j;    // permuted K index (p*16+c)
                int Kc = Kp & 15;                 // channel
                int Kq = Kp >> 4;                 // position
                a[j] = (o < 35) ? (_Float16)fc_w[o * 384 + Kc * 24 + Kq]
                                : (_Float16)0.f;
            }
            A[kt] = a;
        }
    }
    const float fcb = (wid == 9 && lane < 35) ? fc_b[lane] : 0.f;

    // ---------- staging setup (wid 3..8): st in 0..383, 5 floats each ----------
    const int st = tid - 192;
    int fs[5], fl[5];
    if (wid >= 3 && wid < 9) {
#pragma unroll
        for (int r = 0; r < 5; ++r) {
            int f = st + 384 * r;    // 0..1919, exactly covers 64*30
            fs[r] = f / 30;          // t_local 0..63
            fl[r] = f % 30;          // position 0..29
        }
    }

    // ---------- state ----------
    float m1a = 0.f, spa = 0.f;      // LIF1 channel c0
    float m1b = 0.f, spb = 0.f;      // LIF1 channel c0+1
    float mem2 = 0.f, accO = 0.f;    // LIF2 (wave9 lanes<35)
    float xr[5];                     // staging regs, data phase ph+1

    const float* xb = x + (size_t)b * (TN * 30);

    // ---------- prologue (wid 3..8): stage xsT[0]; load regs for data phase 1 ----------
    if (wid >= 3 && wid < 9) {
#pragma unroll
        for (int r = 0; r < 5; ++r) {
            int f = st + 384 * r;
            xsT[0][fl[r]][fs[r]] = xb[f];          // t 0..63 < TN
        }
#pragma unroll
        for (int r = 0; r < 5; ++r) {
            int f = st + 384 * r;
            xr[r] = xb[1920 + f];                  // t 64..127 < TN
        }
    }
    __syncthreads();

#pragma unroll 1
    for (int ph = 0; ph < NIT; ++ph) {
        if (wid < 3) {
            // ========= conv+LIF1(ph): 16 blocks of 4 steps, 2-deep read pipeline =========
            if (ph < 16) {
                const float* xcol = &xsT[ph & 1][p][0];
                unsigned int* sdst =
                    (unsigned int*)&spk[ph & 1][0][p * 16 + c0];

                f32x4 bufA[7], bufB[7];
                LOADBLK(bufA, 0)
#pragma unroll 2
                for (int blk = 0; blk < 16; blk += 2) {
                    const int sB = (blk + 1) * 4;
                    LOADBLK(bufB, sB)
                    CONV4(bufA, blk * 4)
                    const int sA = (blk + 2 < 16) ? (blk + 2) * 4 : 60;
                    LOADBLK(bufA, sA)
                    CONV4(bufB, sB)
                }
            }
        } else if (wid < 9) {
            // ====== staging loads for data phase ph+2 issued first (latency) ======
            const bool ldg = (ph <= 13);
            float xn[5];
            if (ldg) {
                const float* src = xb + (size_t)(ph + 2) * (SPH * 30);
#pragma unroll
                for (int r = 0; r < 5; ++r) {
                    int f = st + 384 * r;
                    int t = (ph + 2) * SPH + fs[r];
                    xn[r] = (t < TN) ? src[f] : 0.f;
                }
            }
            // =================== GEMM(ph-1): tasks (m, tb0) and (m, tb0+2) ===================
            if (ph >= 1 && ph <= 16) {
                const _Float16* sb = &spk[(ph - 1) & 1][0][0];
                float* cd = &c2L[(ph - 1) & 1][0][0];
#pragma unroll
                for (int task = 0; task < 2; ++task) {
                    const int tb = tb0 + task * 2;      // 0..3
                    half8 B[12];
#pragma unroll
                    for (int kt = 0; kt < 12; ++kt)
                        B[kt] = *(const half8*)(sb + (tb * 16 + nL) * SPKW + kt * 32 + q * 8);
                    f32x4 acc = {0.f, 0.f, 0.f, 0.f};
#pragma unroll
                    for (int kt = 0; kt < 12; ++kt)
                        acc = __builtin_amdgcn_mfma_f32_16x16x32_f16(A[kt], B[kt], acc, 0, 0, 0);
                    // C/D: col = lane&15 (t_local), row = q*4+i (o_local)
                    *(f32x4*)(cd + (tb * 16 + nL) * C2W + m * 16 + q * 4) = acc;
                }
            }
            // ====== staging store (data ph+1, loaded last phase); then rotate ======
            if (ph <= 14) {
                float* dst = &xsT[(ph + 1) & 1][0][0];
#pragma unroll
                for (int r = 0; r < 5; ++r)
                    dst[fl[r] * XTW + fs[r]] = xr[r];
            }
            if (ldg) {
#pragma unroll
                for (int r = 0; r < 5; ++r) xr[r] = xn[r];
            }
        } else {
            // =================== LIF2 scan(ph-2) (wave 9 lanes<35) ===================
            if (lane < 35 && ph >= 2) {
                const float* cs = &c2L[(ph - 2) & 1][0][0];
                const int tbase = (ph - 2) * SPH;
#pragma unroll
                for (int jc = 0; jc < SPH; jc += 16) {
                    float v[16];
#pragma unroll
                    for (int u = 0; u < 16; ++u)
                        v[u] = cs[(jc + u) * C2W + lane];
#pragma unroll
                    for (int u = 0; u < 16; ++u) {
                        float r2 = (mem2 > 1.0f) ? 1.0f : 0.0f;
                        mem2 = 0.9f * mem2 + (v[u] + fcb) - r2;
                        if (tbase + jc + u < TN) accO += mem2;
                    }
                }
            }
        }
        __syncthreads();
    }

    if (wid == 9 && lane < 35) out[b * 35 + lane] = accO * (1.0f / (float)TN);
}

extern "C" void kernel_launch(void* const* d_in, const int* in_sizes, int n_in,
                              void* d_out, int out_size, void* d_ws, size_t ws_size,
                              hipStream_t stream) {
    const float* x      = (const float*)d_in[0];
    const float* conv_w = (const float*)d_in[1];
    const float* conv_b = (const float*)d_in[2];
    const float* fc_w   = (const float*)d_in[3];
    const float* fc_b   = (const float*)d_in[4];
    float* out          = (float*)d_out;

    snn_fwd<<<256, 640, 0, stream>>>(x, conv_w, conv_b, fc_w, fc_b, out);
}

// Round 8
// 146.337 us; speedup vs baseline: 1.1196x; 1.1117x over previous
//
#include <hip/hip_runtime.h>

typedef _Float16 half8 __attribute__((ext_vector_type(8)));
typedef float f32x4 __attribute__((ext_vector_type(4)));

#define SPH  32           // timesteps per phase
#define NIT  34           // 32 compute phases + 2 pipeline-drain iterations
#define SPKW 392          // spk row stride f16: 384 + 8 pad (784 B rows, 16B-aligned)
#define XTW  36           // xsT row stride (floats): 144 B rows, 16B-aligned cols
#define C2W  48           // c2L row stride (floats)
#define TN   1000

// R19 = R16 + hand-pipelined conv reads (2-deep, fully unrolled, named bufs).
// R17/R18 (SPH=64) abandoned: VGPR pressure -> scratch spills (20MB writes).
// Model: phase ~ LDS-pipe work + conv VALU, ADDITIVE because conv's per-block
// read->compute chain doesn't overlap (reads queue behind post-barrier burst).
// This round overlaps block i+1's 7 ds_read_b128 with block i's ~150cyc
// compute; only block 0's latency remains exposed per phase.
//   waves 0-2 (192 thr): conv+LIF1(ph), 2 channels/thread (cpair=ct&7, p=ct>>3)
//   waves 3-8 (384 thr): FC GEMM(ph-1) (12 B-loads + 12 MFMA + 1 store)
//                        + xsT staging (3 floats/thread, 2-phase pipeline)
//   wave 3:              LIF2 scan(ph-2) after GEMM + final output.
// One barrier per iteration; producer->consumer 1 barrier apart.

#define LOADBLK(BUF, S)                                                 \
    _Pragma("unroll")                                                   \
    for (int k = 0; k < 7; ++k)                                         \
        BUF[k] = *(const f32x4*)(xcol + k * XTW + (S));

#define CONV4(BUF, SB)                                                  \
    {                                                                   \
        float ca[4], cc[4];                                             \
        _Pragma("unroll")                                               \
        for (int dt = 0; dt < 4; ++dt) { ca[dt] = cb0; cc[dt] = cb1; }  \
        _Pragma("unroll")                                               \
        for (int k = 0; k < 7; ++k) {                                   \
            _Pragma("unroll")                                           \
            for (int dt = 0; dt < 4; ++dt) {                            \
                ca[dt] = fmaf(wk0[k], BUF[k][dt], ca[dt]);              \
                cc[dt] = fmaf(wk1[k], BUF[k][dt], cc[dt]);              \
            }                                                           \
        }                                                               \
        _Pragma("unroll")                                               \
        for (int dt = 0; dt < 4; ++dt) {                                \
            m1a = fmaf(0.9f, m1a, ca[dt] - spa);                        \
            spa = (m1a > 1.0f) ? 1.0f : 0.0f;                           \
            m1b = fmaf(0.9f, m1b, cc[dt] - spb);                        \
            spb = (m1b > 1.0f) ? 1.0f : 0.0f;                           \
            unsigned int pk = (m1a > 1.0f ? 0x00003C00u : 0u) |         \
                              (m1b > 1.0f ? 0x3C000000u : 0u);          \
            sdst[((SB) + dt) * (SPKW / 2)] = pk;                        \
        }                                                               \
    }

__global__ __launch_bounds__(576, 1) void snn_fwd(
    const float* __restrict__ x,      // (256,1000,30)
    const float* __restrict__ conv_w, // (16,1,7)
    const float* __restrict__ conv_b, // (16)
    const float* __restrict__ fc_w,   // (35,384)
    const float* __restrict__ fc_b,   // (35)
    float* __restrict__ out)          // (256,35)
{
    __shared__ __align__(16) _Float16 spk[2][SPH][SPKW];   // 50176 B
    __shared__ __align__(16) float    xsT[2][30][XTW];     //  8640 B
    __shared__ __align__(16) float    c2L[2][SPH][C2W];    // 12288 B

    const int tid  = threadIdx.x;
    const int b    = blockIdx.x;
    const int wid  = tid >> 6;
    const int lane = tid & 63;

    // ---------- conv setup (wid<3): thread = (cpair=ct&7, p=ct>>3), 2 channels ----------
    const int ct    = tid;           // 0..191 when wid<3
    const int cpair = ct & 7;
    const int p     = ct >> 3;       // 0..23
    const int c0    = cpair * 2;
    float wk0[7], wk1[7];
    float cb0 = 0.f, cb1 = 0.f;
    if (wid < 3) {
#pragma unroll
        for (int k = 0; k < 7; ++k) {
            wk0[k] = conv_w[c0 * 7 + k];
            wk1[k] = conv_w[(c0 + 1) * 7 + k];
        }
        cb0 = conv_b[c0];
        cb1 = conv_b[c0 + 1];
    }

    // ---------- FC setup (wid 3..8): g=(wid-3): m=g>>1 (M-tile), tb=g&1 ----------
    const int g  = wid - 3;
    const int m  = g >> 1;
    const int tb = g & 1;
    const int nL = lane & 15;        // B col (t_local); C col
    const int q  = lane >> 4;        // quad: k = q*8 + j
    half8 A[12];
    if (wid >= 3) {
        const int o = m * 16 + nL;
#pragma unroll
        for (int kt = 0; kt < 12; ++kt) {
            half8 a;
#pragma unroll
            for (int j = 0; j < 8; ++j) {
                int Kp = kt * 32 + q * 8 + j;    // permuted K index (p*16+c)
                int Kc = Kp & 15;                 // channel
                int Kq = Kp >> 4;                 // position
                a[j] = (o < 35) ? (_Float16)fc_w[o * 384 + Kc * 24 + Kq]
                                : (_Float16)0.f;
            }
            A[kt] = a;
        }
    }
    const float fcb = (wid == 3 && lane < 35) ? fc_b[lane] : 0.f;

    // ---------- staging setup (wid>=3): st = tid-192 in 0..383, 3 floats each ----------
    const int st = tid - 192;
    int fs[3], fl[3];
    if (wid >= 3) {
#pragma unroll
        for (int r = 0; r < 3; ++r) {
            int f = st + 384 * r;    // 0..1151
            fs[r] = f / 30;
            fl[r] = f % 30;
        }
    }

    // ---------- state ----------
    float m1a = 0.f, spa = 0.f;      // LIF1 channel c0
    float m1b = 0.f, spb = 0.f;      // LIF1 channel c0+1
    float mem2 = 0.f, accO = 0.f;    // LIF2 (wave3 lanes<35)
    float xr[3];                     // staging regs, data phase ph+1

    const float* xb = x + (size_t)b * (TN * 30);

    // ---------- prologue (wid>=3): stage xsT[0]; issue loads for data phase 1 ----------
    if (wid >= 3) {
#pragma unroll
        for (int r = 0; r < 3; ++r) {
            int f = st + 384 * r;
            if (f < 960) xsT[0][fl[r]][fs[r]] = xb[f];     // t < 32 < TN
        }
#pragma unroll
        for (int r = 0; r < 3; ++r) {
            int f = st + 384 * r;
            xr[r] = (f < 960) ? xb[960 + f] : 0.f;         // t < 64 < TN
        }
    }
    __syncthreads();

#pragma unroll 1
    for (int ph = 0; ph < NIT; ++ph) {
        if (wid < 3) {
            // ===== conv+LIF1(ph): 8 blocks of 4 steps, 2-deep read pipeline =====
            if (ph < 32) {
                const float* xcol = &xsT[ph & 1][p][0];
                unsigned int* sdst =
                    (unsigned int*)&spk[ph & 1][0][p * 16 + c0];

                f32x4 bufA[7], bufB[7];
                LOADBLK(bufA, 0)
#pragma unroll
                for (int blk = 0; blk < 8; blk += 2) {
                    LOADBLK(bufB, (blk + 1) * 4)
                    CONV4(bufA, blk * 4)
                    if (blk + 2 < 8) { LOADBLK(bufA, (blk + 2) * 4) }
                    CONV4(bufB, (blk + 1) * 4)
                }
            }
        } else {
            // ====== staging loads for data phase ph+2 issued first (latency) ======
            const bool ldg = (ph <= 29);
            float xn[3];
            if (ldg) {
                const float* src = xb + (size_t)(ph + 2) * (SPH * 30);
#pragma unroll
                for (int r = 0; r < 3; ++r) {
                    int f = st + 384 * r;
                    int t = (ph + 2) * SPH + fs[r];
                    xn[r] = (f < 960 && t < TN) ? src[f] : 0.f;
                }
            }
            // =================== GEMM(ph-1): this wave's (m, tb) ===================
            if (ph >= 1 && ph <= 32) {
                const _Float16* sb = &spk[(ph - 1) & 1][0][0];
                half8 B[12];
#pragma unroll
                for (int kt = 0; kt < 12; ++kt)
                    B[kt] = *(const half8*)(sb + (tb * 16 + nL) * SPKW + kt * 32 + q * 8);
                f32x4 acc = {0.f, 0.f, 0.f, 0.f};
#pragma unroll
                for (int kt = 0; kt < 12; ++kt)
                    acc = __builtin_amdgcn_mfma_f32_16x16x32_f16(A[kt], B[kt], acc, 0, 0, 0);
                // C/D: col = lane&15 (t_local), row = q*4+i (o_local)
                float* cd = &c2L[(ph - 1) & 1][0][0];
                *(f32x4*)(cd + (tb * 16 + nL) * C2W + m * 16 + q * 4) = acc;
            }
            // =================== LIF2 scan(ph-2) (wave 3 lanes<35) ===================
            if (wid == 3 && lane < 35 && ph >= 2) {
                const float* cs = &c2L[(ph - 2) & 1][0][0];
                float v[SPH];
#pragma unroll
                for (int j = 0; j < SPH; ++j) v[j] = cs[j * C2W + lane];
                const int tbase = (ph - 2) * SPH;
#pragma unroll
                for (int j = 0; j < SPH; ++j) {
                    float r2 = (mem2 > 1.0f) ? 1.0f : 0.0f;
                    mem2 = 0.9f * mem2 + (v[j] + fcb) - r2;
                    if (tbase + j < TN) accO += mem2;
                }
            }
            // ====== staging store (data ph+1, loaded last phase); then rotate ======
            if (ph <= 30) {
                float* dst = &xsT[(ph + 1) & 1][0][0];
#pragma unroll
                for (int r = 0; r < 3; ++r) {
                    int f = st + 384 * r;
                    if (f < 960) dst[fl[r] * XTW + fs[r]] = xr[r];
                }
            }
            if (ldg) {
#pragma unroll
                for (int r = 0; r < 3; ++r) xr[r] = xn[r];
            }
        }
        __syncthreads();
    }

    if (wid == 3 && lane < 35) out[b * 35 + lane] = accO * (1.0f / (float)TN);
}

extern "C" void kernel_launch(void* const* d_in, const int* in_sizes, int n_in,
                              void* d_out, int out_size, void* d_ws, size_t ws_size,
                              hipStream_t stream) {
    const float* x      = (const float*)d_in[0];
    const float* conv_w = (const float*)d_in[1];
    const float* conv_b = (const float*)d_in[2];
    const float* fc_w   = (const float*)d_in[3];
    const float* fc_b   = (const float*)d_in[4];
    float* out          = (float*)d_out;

    snn_fwd<<<256, 576, 0, stream>>>(x, conv_w, conv_b, fc_w, fc_b, out);
}